// Round 5
// baseline (294.324 us; speedup 1.0000x reference)
//
#include <hip/hip_runtime.h>
#include <hip/hip_bf16.h>
#include <stdint.h>

#define NN 2048
#define BK 32

typedef __bf16 bf16;
typedef __bf16 bf16x8 __attribute__((ext_vector_type(8)));
typedef __bf16 bf16x4 __attribute__((ext_vector_type(4)));
typedef float f32x4 __attribute__((ext_vector_type(4)));

// async global->LDS, 16B per lane (LDS dest = wave-uniform base + lane*16)
__device__ __forceinline__ void async_copy16(bf16* lds, const bf16* g) {
    __builtin_amdgcn_global_load_lds(
        (const __attribute__((address_space(1))) unsigned int*)g,
        (__attribute__((address_space(3))) unsigned int*)lds,
        16, 0, 0);
}

// fine-grained waits + compiler-visible barrier (no vmcnt(0) drain)
#define WAIT_VM(n) asm volatile("s_waitcnt vmcnt(" #n ")" ::: "memory")
#define BAR()                                  \
    do {                                       \
        asm volatile("" ::: "memory");         \
        __builtin_amdgcn_s_barrier();          \
        asm volatile("" ::: "memory");         \
    } while (0)

// ---------------------------------------------------------------------------
// fp32 -> bf16 transpose cast, z-batched. 64x64 tile, 256 threads.
// ---------------------------------------------------------------------------
struct CastArgs {
    const float* in[4];
    bf16*        outT[4];
    bf16*        outN[4];
};

__global__ __launch_bounds__(256) void transpose_cast_kernel(CastArgs args) {
    const float* __restrict__ in = args.in[blockIdx.z];
    bf16* __restrict__ outT      = args.outT[blockIdx.z];
    bf16* __restrict__ outN      = args.outN[blockIdx.z];
    __shared__ float tile[64][65];
    const int bx = blockIdx.x * 64;   // col base
    const int by = blockIdx.y * 64;   // row base
    const int t  = threadIdx.x;
    const int tc = t & 15, tr = t >> 4;
#pragma unroll
    for (int p = 0; p < 4; ++p) {
        const int r = tr + p * 16;
        const float4 v = *(const float4*)&in[(size_t)(by + r) * NN + bx + tc * 4];
        tile[r][tc * 4 + 0] = v.x; tile[r][tc * 4 + 1] = v.y;
        tile[r][tc * 4 + 2] = v.z; tile[r][tc * 4 + 3] = v.w;
        if (outN) {
            bf16x4 b = {(bf16)v.x, (bf16)v.y, (bf16)v.z, (bf16)v.w};
            *(bf16x4*)&outN[(size_t)(by + r) * NN + bx + tc * 4] = b;
        }
    }
    __syncthreads();
    const int cc = t >> 2, e = t & 3;
#pragma unroll
    for (int u = 0; u < 2; ++u) {
        const int r0 = e * 16 + u * 8;
        bf16x8 b;
#pragma unroll
        for (int i = 0; i < 8; ++i) b[i] = (bf16)tile[r0 + i][cc];
        *(bf16x8*)&outT[(size_t)(bx + cc) * NN + by + r0] = b;
    }
}

// ---------------------------------------------------------------------------
// Phase 1: batched GEMM, 64x64 tile, BK=32, depth-3 pipeline, 4 waves each
// computing 32x32 (2x2 MFMAs). z picks {M1, M2, M3}. z==0 epilogue also
// emits M1bf = bf16(M1) and B1bf = bf16(M1*W1) (fused post_m1).
// ---------------------------------------------------------------------------
struct Gemm3Args {
    const bf16*  A[3];
    const bf16*  Bt[3];
    float*       C[3];
    const float* W1;
    bf16*        M1bf;
    bf16*        B1bf;
};

__global__ __launch_bounds__(256) void gemm3_kernel(Gemm3Args args) {
    const bf16* __restrict__ A  = args.A[blockIdx.z];
    const bf16* __restrict__ Bt = args.Bt[blockIdx.z];
    float* __restrict__ C       = args.C[blockIdx.z];

    __shared__ bf16 As0[64 * BK], As1[64 * BK], As2[64 * BK];
    __shared__ bf16 Bs0[64 * BK], Bs1[64 * BK], Bs2[64 * BK];

    const int t  = threadIdx.x;
    const int bm = blockIdx.x * 64;
    const int bn = blockIdx.y * 64;

    const int row0 = t >> 2;                       // 0..63
    const int qp   = t & 3;
    const int col0 = ((qp ^ ((row0 >> 1) & 3)) << 3);  // XOR swizzle
    const int off0 = t * 8;

    const bf16* gA0 = A  + (size_t)(bm + row0) * NN + col0;
    const bf16* gB0 = Bt + (size_t)(bn + row0) * NN + col0;

    const int wave = t >> 6;
    const int lane = t & 63;
    const int wm   = (wave >> 1) * 32;
    const int wn   = (wave & 1) * 32;
    const int lrow = lane & 15;
    const int q    = lane >> 4;
    const int qe   = (q ^ ((lrow >> 1) & 3)) << 3;

    f32x4 acc[2][2];
#pragma unroll
    for (int i = 0; i < 2; ++i)
#pragma unroll
        for (int j = 0; j < 2; ++j) acc[i][j] = (f32x4){0.f, 0.f, 0.f, 0.f};

    auto issue = [&](bf16* As, bf16* Bs, int kt) {
        const int kof = kt * BK;
        async_copy16(&As[off0], gA0 + kof);
        async_copy16(&Bs[off0], gB0 + kof);
    };
    auto compute = [&](const bf16* As, const bf16* Bs) {
        bf16x8 af[2], bfr[2];
#pragma unroll
        for (int i = 0; i < 2; ++i)
            af[i] = *(const bf16x8*)&As[(wm + i * 16 + lrow) * BK + qe];
#pragma unroll
        for (int j = 0; j < 2; ++j)
            bfr[j] = *(const bf16x8*)&Bs[(wn + j * 16 + lrow) * BK + qe];
#pragma unroll
        for (int i = 0; i < 2; ++i)
#pragma unroll
            for (int j = 0; j < 2; ++j)
                acc[i][j] = __builtin_amdgcn_mfma_f32_16x16x32_bf16(
                    af[i], bfr[j], acc[i][j], 0, 0, 0);
    };

    issue(As0, Bs0, 0);
    issue(As1, Bs1, 1);
#pragma unroll 1
    for (int kt = 0; kt < 60; kt += 3) {
        issue(As2, Bs2, kt + 2); WAIT_VM(4); BAR(); compute(As0, Bs0); BAR();
        issue(As0, Bs0, kt + 3); WAIT_VM(4); BAR(); compute(As1, Bs1); BAR();
        issue(As1, Bs1, kt + 4); WAIT_VM(4); BAR(); compute(As2, Bs2); BAR();
    }
    issue(As2, Bs2, 62); WAIT_VM(4); BAR(); compute(As0, Bs0); BAR();
    issue(As0, Bs0, 63); WAIT_VM(4); BAR(); compute(As1, Bs1); BAR();
    WAIT_VM(2); BAR(); compute(As2, Bs2); BAR();
    WAIT_VM(0); BAR(); compute(As0, Bs0);

    // C/D layout: col = lane&15, row = q*4 + reg
    const int z = blockIdx.z;
#pragma unroll
    for (int i = 0; i < 2; ++i)
#pragma unroll
        for (int j = 0; j < 2; ++j)
#pragma unroll
            for (int r = 0; r < 4; ++r) {
                const size_t idx = (size_t)(bm + wm + i * 16 + q * 4 + r) * NN +
                                   (bn + wn + j * 16 + lrow);
                const float v = acc[i][j][r];
                C[idx] = v;
                if (z == 0) {
                    const float w = args.W1[idx];
                    args.M1bf[idx] = (bf16)v;
                    args.B1bf[idx] = (bf16)(v * w);
                }
            }
}

// ---------------------------------------------------------------------------
// Phase 2: fused dual GEMM + final epilogue. Per 64x64 tile:
//   m5 = M1bf @ A   (A given as At = A^T)
//   m4 = B1bf @ A
//   out = M1*M2 + M1 + M3 + M3*(m4*W1)*(M3 + m5)    (M2 resides in out)
// Shared B-tile staging across both GEMMs. depth-3 pipeline, 36 KB LDS.
// ---------------------------------------------------------------------------
struct Gemm2Args {
    const bf16*  M1bf;
    const bf16*  B1bf;
    const bf16*  At;
    const float* M1;
    const float* M3;
    const float* W1;
    float*       out;
};

__global__ __launch_bounds__(256) void gemm2_fused_kernel(Gemm2Args args) {
    __shared__ bf16 A50[64 * BK], A51[64 * BK], A52[64 * BK];
    __shared__ bf16 A40[64 * BK], A41[64 * BK], A42[64 * BK];
    __shared__ bf16 Bs0[64 * BK], Bs1[64 * BK], Bs2[64 * BK];

    const int t  = threadIdx.x;
    const int bm = blockIdx.x * 64;
    const int bn = blockIdx.y * 64;

    const int row0 = t >> 2;
    const int qp   = t & 3;
    const int col0 = ((qp ^ ((row0 >> 1) & 3)) << 3);
    const int off0 = t * 8;

    const bf16* g5 = args.M1bf + (size_t)(bm + row0) * NN + col0;
    const bf16* g4 = args.B1bf + (size_t)(bm + row0) * NN + col0;
    const bf16* gB = args.At   + (size_t)(bn + row0) * NN + col0;

    const int wave = t >> 6;
    const int lane = t & 63;
    const int wm   = (wave >> 1) * 32;
    const int wn   = (wave & 1) * 32;
    const int lrow = lane & 15;
    const int q    = lane >> 4;
    const int qe   = (q ^ ((lrow >> 1) & 3)) << 3;

    f32x4 acc5[2][2], acc4[2][2];
#pragma unroll
    for (int i = 0; i < 2; ++i)
#pragma unroll
        for (int j = 0; j < 2; ++j) {
            acc5[i][j] = (f32x4){0.f, 0.f, 0.f, 0.f};
            acc4[i][j] = (f32x4){0.f, 0.f, 0.f, 0.f};
        }

    auto issue = [&](bf16* A5, bf16* A4, bf16* Bs, int kt) {
        const int kof = kt * BK;
        async_copy16(&A5[off0], g5 + kof);
        async_copy16(&A4[off0], g4 + kof);
        async_copy16(&Bs[off0], gB + kof);
    };
    auto compute = [&](const bf16* A5, const bf16* A4, const bf16* Bs) {
        bf16x8 a5[2], a4[2], bfr[2];
#pragma unroll
        for (int i = 0; i < 2; ++i) {
            a5[i] = *(const bf16x8*)&A5[(wm + i * 16 + lrow) * BK + qe];
            a4[i] = *(const bf16x8*)&A4[(wm + i * 16 + lrow) * BK + qe];
        }
#pragma unroll
        for (int j = 0; j < 2; ++j)
            bfr[j] = *(const bf16x8*)&Bs[(wn + j * 16 + lrow) * BK + qe];
#pragma unroll
        for (int i = 0; i < 2; ++i)
#pragma unroll
            for (int j = 0; j < 2; ++j) {
                acc5[i][j] = __builtin_amdgcn_mfma_f32_16x16x32_bf16(
                    a5[i], bfr[j], acc5[i][j], 0, 0, 0);
                acc4[i][j] = __builtin_amdgcn_mfma_f32_16x16x32_bf16(
                    a4[i], bfr[j], acc4[i][j], 0, 0, 0);
            }
    };

    issue(A50, A40, Bs0, 0);
    issue(A51, A41, Bs1, 1);
#pragma unroll 1
    for (int kt = 0; kt < 60; kt += 3) {
        issue(A52, A42, Bs2, kt + 2); WAIT_VM(6); BAR(); compute(A50, A40, Bs0); BAR();
        issue(A50, A40, Bs0, kt + 3); WAIT_VM(6); BAR(); compute(A51, A41, Bs1); BAR();
        issue(A51, A41, Bs1, kt + 4); WAIT_VM(6); BAR(); compute(A52, A42, Bs2); BAR();
    }
    issue(A52, A42, Bs2, 62); WAIT_VM(6); BAR(); compute(A50, A40, Bs0); BAR();
    issue(A50, A40, Bs0, 63); WAIT_VM(6); BAR(); compute(A51, A41, Bs1); BAR();
    WAIT_VM(3); BAR(); compute(A52, A42, Bs2); BAR();
    WAIT_VM(0); BAR(); compute(A50, A40, Bs0);

    // epilogue: out = M1*M2 + M1 + M3 + M3*(m4*W1)*(M3 + m5)
#pragma unroll
    for (int i = 0; i < 2; ++i)
#pragma unroll
        for (int j = 0; j < 2; ++j)
#pragma unroll
            for (int r = 0; r < 4; ++r) {
                const size_t idx = (size_t)(bm + wm + i * 16 + q * 4 + r) * NN +
                                   (bn + wn + j * 16 + lrow);
                const float m5 = acc5[i][j][r];
                const float m4 = acc4[i][j][r];
                const float m1 = args.M1[idx];
                const float m3 = args.M3[idx];
                const float w1 = args.W1[idx];
                const float m2 = args.out[idx];
                args.out[idx] =
                    m1 * m2 + m1 + m3 + m3 * (m4 * w1) * (m3 + m5);
            }
}

// ---------------------------------------------------------------------------
extern "C" void kernel_launch(void* const* d_in, const int* in_sizes, int n_in,
                              void* d_out, int out_size, void* d_ws, size_t ws_size,
                              hipStream_t stream) {
    const float* A  = (const float*)d_in[0];
    const float* W1 = (const float*)d_in[1];
    const float* W2 = (const float*)d_in[2];
    const float* W3 = (const float*)d_in[3];
    float* out = (float*)d_out;

    const size_t P = (size_t)NN * NN;
    char* ws = (char*)d_ws;

    bf16* Abf  = (bf16*)ws;            // P*2 bytes each
    bf16* At   = Abf + P;
    bf16* W1t  = At + P;
    bf16* W2t  = W1t + P;
    bf16* W3bf = W2t + P;
    bf16* W3t  = W3bf + P;
    bf16* M1bf = W3t + P;
    bf16* B1bf = M1bf + P;
    float* M1  = (float*)(B1bf + P);   // P*4 bytes each
    float* M3  = M1 + P;
    // total: 8*2*P + 2*4*P = 24*P = 96 MiB

    CastArgs ca;
    ca.in[0] = A;  ca.outT[0] = At;  ca.outN[0] = Abf;
    ca.in[1] = W1; ca.outT[1] = W1t; ca.outN[1] = nullptr;
    ca.in[2] = W2; ca.outT[2] = W2t; ca.outN[2] = nullptr;
    ca.in[3] = W3; ca.outT[3] = W3t; ca.outN[3] = W3bf;
    transpose_cast_kernel<<<dim3(NN / 64, NN / 64, 4), 256, 0, stream>>>(ca);

    // phase 1: M1 = A@W1 (+ fused M1bf/B1bf), M2(out) = A@W2, M3 = W3@W3
    Gemm3Args g3;
    g3.A[0] = Abf;  g3.Bt[0] = W1t; g3.C[0] = M1;
    g3.A[1] = Abf;  g3.Bt[1] = W2t; g3.C[1] = out;
    g3.A[2] = W3bf; g3.Bt[2] = W3t; g3.C[2] = M3;
    g3.W1 = W1; g3.M1bf = M1bf; g3.B1bf = B1bf;
    gemm3_kernel<<<dim3(NN / 64, NN / 64, 3), 256, 0, stream>>>(g3);

    // phase 2: fused dual GEMM (M5 = M1@A, M4 = (M1*W1)@A) + final epilogue
    Gemm2Args g2;
    g2.M1bf = M1bf; g2.B1bf = B1bf; g2.At = At;
    g2.M1 = M1; g2.M3 = M3; g2.W1 = W1; g2.out = out;
    gemm2_fused_kernel<<<dim3(NN / 64, NN / 64), 256, 0, stream>>>(g2);
}

// Round 6
// 258.603 us; speedup vs baseline: 1.1381x; 1.1381x over previous
//
#include <hip/hip_runtime.h>
#include <hip/hip_bf16.h>
#include <stdint.h>

#define NN 2048
#define BK 32

typedef __bf16 bf16;
typedef __bf16 bf16x8 __attribute__((ext_vector_type(8)));
typedef __bf16 bf16x4 __attribute__((ext_vector_type(4)));
typedef float f32x4 __attribute__((ext_vector_type(4)));

// async global->LDS, 16B per lane (LDS dest = wave-uniform base + lane*16)
__device__ __forceinline__ void async_copy16(bf16* lds, const bf16* g) {
    __builtin_amdgcn_global_load_lds(
        (const __attribute__((address_space(1))) unsigned int*)g,
        (__attribute__((address_space(3))) unsigned int*)lds,
        16, 0, 0);
}

// fine-grained waits + compiler-visible barrier (no vmcnt(0) drain)
#define WAIT_VM(n) asm volatile("s_waitcnt vmcnt(" #n ")" ::: "memory")
#define BAR()                                  \
    do {                                       \
        asm volatile("" ::: "memory");         \
        __builtin_amdgcn_s_barrier();          \
        asm volatile("" ::: "memory");         \
    } while (0)

// ---------------------------------------------------------------------------
// fp32 -> bf16 transpose cast, z-batched. 64x64 tile, 256 threads.
// ---------------------------------------------------------------------------
struct CastArgs {
    const float* in[4];
    bf16*        outT[4];
    bf16*        outN[4];
};

__global__ __launch_bounds__(256) void transpose_cast_kernel(CastArgs args) {
    const float* __restrict__ in = args.in[blockIdx.z];
    bf16* __restrict__ outT      = args.outT[blockIdx.z];
    bf16* __restrict__ outN      = args.outN[blockIdx.z];
    __shared__ float tile[64][65];
    const int bx = blockIdx.x * 64;   // col base
    const int by = blockIdx.y * 64;   // row base
    const int t  = threadIdx.x;
    const int tc = t & 15, tr = t >> 4;
#pragma unroll
    for (int p = 0; p < 4; ++p) {
        const int r = tr + p * 16;
        const float4 v = *(const float4*)&in[(size_t)(by + r) * NN + bx + tc * 4];
        tile[r][tc * 4 + 0] = v.x; tile[r][tc * 4 + 1] = v.y;
        tile[r][tc * 4 + 2] = v.z; tile[r][tc * 4 + 3] = v.w;
        if (outN) {
            bf16x4 b = {(bf16)v.x, (bf16)v.y, (bf16)v.z, (bf16)v.w};
            *(bf16x4*)&outN[(size_t)(by + r) * NN + bx + tc * 4] = b;
        }
    }
    __syncthreads();
    const int cc = t >> 2, e = t & 3;
#pragma unroll
    for (int u = 0; u < 2; ++u) {
        const int r0 = e * 16 + u * 8;
        bf16x8 b;
#pragma unroll
        for (int i = 0; i < 8; ++i) b[i] = (bf16)tile[r0 + i][cc];
        *(bf16x8*)&outT[(size_t)(bx + cc) * NN + by + r0] = b;
    }
}

// ---------------------------------------------------------------------------
// Phase 1: batched GEMM, 128x128 tile, BK=32, depth-3 pipeline, 4 waves each
// computing 64x64 (4x4 MFMAs).  z picks {M1, M2, M3}.  z==0 also emits
// M1bf = bf16(M1), B1bf = bf16(M1*W1)  (fused post_m1).
// ---------------------------------------------------------------------------
struct Gemm3Args {
    const bf16*  A[3];
    const bf16*  Bt[3];
    float*       C[3];
    const float* W1;
    bf16*        M1bf;
    bf16*        B1bf;
};

__global__ __launch_bounds__(256) void gemm3_kernel(Gemm3Args args) {
    const bf16* __restrict__ A  = args.A[blockIdx.z];
    const bf16* __restrict__ Bt = args.Bt[blockIdx.z];
    float* __restrict__ C       = args.C[blockIdx.z];

    __shared__ bf16 As0[128 * BK], As1[128 * BK], As2[128 * BK];
    __shared__ bf16 Bs0[128 * BK], Bs1[128 * BK], Bs2[128 * BK];

    const int t  = threadIdx.x;
    const int bm = blockIdx.x * 128;
    const int bn = blockIdx.y * 128;

    const int row0 = t >> 2;                           // 0..63
    const int qp   = t & 3;
    const int col0 = ((qp ^ ((row0 >> 1) & 3)) << 3);  // XOR swizzle
    const int off0 = t * 8;

    const bf16* gA0 = A  + (size_t)(bm + row0) * NN + col0;
    const bf16* gB0 = Bt + (size_t)(bn + row0) * NN + col0;

    const int wave = t >> 6;
    const int lane = t & 63;
    const int wm   = (wave >> 1) * 64;
    const int wn   = (wave & 1) * 64;
    const int lrow = lane & 15;
    const int q    = lane >> 4;
    const int qe   = (q ^ ((lrow >> 1) & 3)) << 3;

    f32x4 acc[4][4];
#pragma unroll
    for (int i = 0; i < 4; ++i)
#pragma unroll
        for (int j = 0; j < 4; ++j) acc[i][j] = (f32x4){0.f, 0.f, 0.f, 0.f};

    auto issue = [&](bf16* As, bf16* Bs, int kt) {
        const int kof = kt * BK;
        async_copy16(&As[off0],           gA0 + kof);
        async_copy16(&As[off0 + 64 * BK], gA0 + (size_t)64 * NN + kof);
        async_copy16(&Bs[off0],           gB0 + kof);
        async_copy16(&Bs[off0 + 64 * BK], gB0 + (size_t)64 * NN + kof);
    };
    auto compute = [&](const bf16* As, const bf16* Bs) {
        bf16x8 af[4], bfr[4];
#pragma unroll
        for (int i = 0; i < 4; ++i)
            af[i] = *(const bf16x8*)&As[(wm + i * 16 + lrow) * BK + qe];
#pragma unroll
        for (int j = 0; j < 4; ++j)
            bfr[j] = *(const bf16x8*)&Bs[(wn + j * 16 + lrow) * BK + qe];
#pragma unroll
        for (int i = 0; i < 4; ++i)
#pragma unroll
            for (int j = 0; j < 4; ++j)
                acc[i][j] = __builtin_amdgcn_mfma_f32_16x16x32_bf16(
                    af[i], bfr[j], acc[i][j], 0, 0, 0);
    };

    issue(As0, Bs0, 0);
    issue(As1, Bs1, 1);
#pragma unroll 1
    for (int kt = 0; kt < 60; kt += 3) {
        issue(As2, Bs2, kt + 2); WAIT_VM(8); BAR(); compute(As0, Bs0); BAR();
        issue(As0, Bs0, kt + 3); WAIT_VM(8); BAR(); compute(As1, Bs1); BAR();
        issue(As1, Bs1, kt + 4); WAIT_VM(8); BAR(); compute(As2, Bs2); BAR();
    }
    issue(As2, Bs2, 62); WAIT_VM(8); BAR(); compute(As0, Bs0); BAR();
    issue(As0, Bs0, 63); WAIT_VM(8); BAR(); compute(As1, Bs1); BAR();
    WAIT_VM(4); BAR(); compute(As2, Bs2); BAR();
    WAIT_VM(0); BAR(); compute(As0, Bs0);

    // C/D layout: col = lane&15, row = q*4 + reg
    const int z = blockIdx.z;
#pragma unroll
    for (int i = 0; i < 4; ++i)
#pragma unroll
        for (int j = 0; j < 4; ++j)
#pragma unroll
            for (int r = 0; r < 4; ++r) {
                const size_t idx = (size_t)(bm + wm + i * 16 + q * 4 + r) * NN +
                                   (bn + wn + j * 16 + lrow);
                const float v = acc[i][j][r];
                C[idx] = v;
                if (z == 0) {
                    const float w = args.W1[idx];
                    args.M1bf[idx] = (bf16)v;
                    args.B1bf[idx] = (bf16)(v * w);
                }
            }
}

// ---------------------------------------------------------------------------
// Phase 2: fused dual GEMM + final epilogue, 128x64 tile, BK=32, depth-3.
// Per tile:  m5 = M1bf @ A,  m4 = B1bf @ A   (A given as At = A^T),
// shared B staging; then out = M1*M2 + M1 + M3 + M3*(m4*W1)*(M3 + m5)
// (M2 resides in out).  LDS 60 KB -> 2 blocks/CU, grid 512 = 2/CU.
// Waves tile 2x2: each wave 64x32 per matrix (4x2 MFMAs x2 = 16 MFMA/step).
// ---------------------------------------------------------------------------
struct Gemm2Args {
    const bf16*  M1bf;
    const bf16*  B1bf;
    const bf16*  At;
    const float* M1;
    const float* M3;
    const float* W1;
    float*       out;
};

__global__ __launch_bounds__(256) void gemm2_fused_kernel(Gemm2Args args) {
    __shared__ bf16 A50[128 * BK], A51[128 * BK], A52[128 * BK];  // M1bf tiles
    __shared__ bf16 A40[128 * BK], A41[128 * BK], A42[128 * BK];  // B1bf tiles
    __shared__ bf16 Bs0[64 * BK],  Bs1[64 * BK],  Bs2[64 * BK];   // At tiles

    const int t  = threadIdx.x;
    const int bm = blockIdx.x * 128;
    const int bn = blockIdx.y * 64;

    const int row0 = t >> 2;
    const int qp   = t & 3;
    const int col0 = ((qp ^ ((row0 >> 1) & 3)) << 3);
    const int off0 = t * 8;

    const bf16* g5 = args.M1bf + (size_t)(bm + row0) * NN + col0;
    const bf16* g4 = args.B1bf + (size_t)(bm + row0) * NN + col0;
    const bf16* gB = args.At   + (size_t)(bn + row0) * NN + col0;

    const int wave = t >> 6;
    const int lane = t & 63;
    const int wm   = (wave >> 1) * 64;   // 0 or 64
    const int wn   = (wave & 1) * 32;    // 0 or 32
    const int lrow = lane & 15;
    const int q    = lane >> 4;
    const int qe   = (q ^ ((lrow >> 1) & 3)) << 3;

    f32x4 acc5[4][2], acc4[4][2];
#pragma unroll
    for (int i = 0; i < 4; ++i)
#pragma unroll
        for (int j = 0; j < 2; ++j) {
            acc5[i][j] = (f32x4){0.f, 0.f, 0.f, 0.f};
            acc4[i][j] = (f32x4){0.f, 0.f, 0.f, 0.f};
        }

    auto issue = [&](bf16* A5, bf16* A4, bf16* Bs, int kt) {
        const int kof = kt * BK;
        async_copy16(&A5[off0],           g5 + kof);
        async_copy16(&A5[off0 + 64 * BK], g5 + (size_t)64 * NN + kof);
        async_copy16(&A4[off0],           g4 + kof);
        async_copy16(&A4[off0 + 64 * BK], g4 + (size_t)64 * NN + kof);
        async_copy16(&Bs[off0],           gB + kof);
    };
    auto compute = [&](const bf16* A5, const bf16* A4, const bf16* Bs) {
        bf16x8 a5[4], a4[4], bfr[2];
#pragma unroll
        for (int i = 0; i < 4; ++i) {
            a5[i] = *(const bf16x8*)&A5[(wm + i * 16 + lrow) * BK + qe];
            a4[i] = *(const bf16x8*)&A4[(wm + i * 16 + lrow) * BK + qe];
        }
#pragma unroll
        for (int j = 0; j < 2; ++j)
            bfr[j] = *(const bf16x8*)&Bs[(wn + j * 16 + lrow) * BK + qe];
#pragma unroll
        for (int i = 0; i < 4; ++i)
#pragma unroll
            for (int j = 0; j < 2; ++j) {
                acc5[i][j] = __builtin_amdgcn_mfma_f32_16x16x32_bf16(
                    a5[i], bfr[j], acc5[i][j], 0, 0, 0);
                acc4[i][j] = __builtin_amdgcn_mfma_f32_16x16x32_bf16(
                    a4[i], bfr[j], acc4[i][j], 0, 0, 0);
            }
    };

    issue(A50, A40, Bs0, 0);
    issue(A51, A41, Bs1, 1);
#pragma unroll 1
    for (int kt = 0; kt < 60; kt += 3) {
        issue(A52, A42, Bs2, kt + 2); WAIT_VM(10); BAR(); compute(A50, A40, Bs0); BAR();
        issue(A50, A40, Bs0, kt + 3); WAIT_VM(10); BAR(); compute(A51, A41, Bs1); BAR();
        issue(A51, A41, Bs1, kt + 4); WAIT_VM(10); BAR(); compute(A52, A42, Bs2); BAR();
    }
    issue(A52, A42, Bs2, 62); WAIT_VM(10); BAR(); compute(A50, A40, Bs0); BAR();
    issue(A50, A40, Bs0, 63); WAIT_VM(10); BAR(); compute(A51, A41, Bs1); BAR();
    WAIT_VM(5); BAR(); compute(A52, A42, Bs2); BAR();
    WAIT_VM(0); BAR(); compute(A50, A40, Bs0);

    // fused final epilogue: out = M1*M2 + M1 + M3 + M3*(m4*W1)*(M3 + m5)
#pragma unroll
    for (int i = 0; i < 4; ++i)
#pragma unroll
        for (int j = 0; j < 2; ++j)
#pragma unroll
            for (int r = 0; r < 4; ++r) {
                const size_t idx = (size_t)(bm + wm + i * 16 + q * 4 + r) * NN +
                                   (bn + wn + j * 16 + lrow);
                const float m5 = acc5[i][j][r];
                const float m4 = acc4[i][j][r];
                const float m1 = args.M1[idx];
                const float m3 = args.M3[idx];
                const float w1 = args.W1[idx];
                const float m2 = args.out[idx];
                args.out[idx] =
                    m1 * m2 + m1 + m3 + m3 * (m4 * w1) * (m3 + m5);
            }
}

// ---------------------------------------------------------------------------
extern "C" void kernel_launch(void* const* d_in, const int* in_sizes, int n_in,
                              void* d_out, int out_size, void* d_ws, size_t ws_size,
                              hipStream_t stream) {
    const float* A  = (const float*)d_in[0];
    const float* W1 = (const float*)d_in[1];
    const float* W2 = (const float*)d_in[2];
    const float* W3 = (const float*)d_in[3];
    float* out = (float*)d_out;

    const size_t P = (size_t)NN * NN;
    char* ws = (char*)d_ws;

    bf16* Abf  = (bf16*)ws;            // P*2 bytes each
    bf16* At   = Abf + P;
    bf16* W1t  = At + P;
    bf16* W2t  = W1t + P;
    bf16* W3bf = W2t + P;
    bf16* W3t  = W3bf + P;
    bf16* M1bf = W3t + P;
    bf16* B1bf = M1bf + P;
    float* M1  = (float*)(B1bf + P);   // P*4 bytes each
    float* M3  = M1 + P;
    // total: 8*2*P + 2*4*P = 24*P = 96 MiB

    CastArgs ca;
    ca.in[0] = A;  ca.outT[0] = At;  ca.outN[0] = Abf;
    ca.in[1] = W1; ca.outT[1] = W1t; ca.outN[1] = nullptr;
    ca.in[2] = W2; ca.outT[2] = W2t; ca.outN[2] = nullptr;
    ca.in[3] = W3; ca.outT[3] = W3t; ca.outN[3] = W3bf;
    transpose_cast_kernel<<<dim3(NN / 64, NN / 64, 4), 256, 0, stream>>>(ca);

    // phase 1: M1 = A@W1 (+ fused M1bf/B1bf), M2(out) = A@W2, M3 = W3@W3
    Gemm3Args g3;
    g3.A[0] = Abf;  g3.Bt[0] = W1t; g3.C[0] = M1;
    g3.A[1] = Abf;  g3.Bt[1] = W2t; g3.C[1] = out;
    g3.A[2] = W3bf; g3.Bt[2] = W3t; g3.C[2] = M3;
    g3.W1 = W1; g3.M1bf = M1bf; g3.B1bf = B1bf;
    gemm3_kernel<<<dim3(NN / 128, NN / 128, 3), 256, 0, stream>>>(g3);

    // phase 2: fused dual GEMM (m5 = M1@A, m4 = (M1*W1)@A) + final epilogue
    Gemm2Args g2;
    g2.M1bf = M1bf; g2.B1bf = B1bf; g2.At = At;
    g2.M1 = M1; g2.M3 = M3; g2.W1 = W1; g2.out = out;
    gemm2_fused_kernel<<<dim3(NN / 128, NN / 64), 256, 0, stream>>>(g2);
}

// Round 7
// 232.401 us; speedup vs baseline: 1.2665x; 1.1127x over previous
//
#include <hip/hip_runtime.h>
#include <hip/hip_bf16.h>
#include <stdint.h>

#define NN 2048
#define BK 32

typedef __bf16 bf16;
typedef __bf16 bf16x8 __attribute__((ext_vector_type(8)));
typedef __bf16 bf16x4 __attribute__((ext_vector_type(4)));
typedef float f32x4 __attribute__((ext_vector_type(4)));

// async global->LDS, 16B per lane (LDS dest = wave-uniform base + lane*16)
__device__ __forceinline__ void async_copy16(bf16* lds, const bf16* g) {
    __builtin_amdgcn_global_load_lds(
        (const __attribute__((address_space(1))) unsigned int*)g,
        (__attribute__((address_space(3))) unsigned int*)lds,
        16, 0, 0);
}

// fine-grained waits + compiler-visible barrier (no vmcnt(0) drain).
// WAIT must precede BAR: each wave drains ITS OWN tile-k DMA before the
// barrier; after the barrier everyone's tile-k data is in LDS.
#define WAIT_VM(n) asm volatile("s_waitcnt vmcnt(" #n ")" ::: "memory")
#define BAR()                                  \
    do {                                       \
        asm volatile("" ::: "memory");         \
        __builtin_amdgcn_s_barrier();          \
        asm volatile("" ::: "memory");         \
    } while (0)

// ---------------------------------------------------------------------------
// fp32 -> bf16 transpose cast, z-batched. 64x64 tile, 256 threads.
// Coalesced transposed stores: 8 lanes write one 128-B contiguous row chunk.
// ---------------------------------------------------------------------------
struct CastArgs {
    const float* in[4];
    bf16*        outT[4];
    bf16*        outN[4];
};

__global__ __launch_bounds__(256) void transpose_cast_kernel(CastArgs args) {
    const float* __restrict__ in = args.in[blockIdx.z];
    bf16* __restrict__ outT      = args.outT[blockIdx.z];
    bf16* __restrict__ outN      = args.outN[blockIdx.z];
    __shared__ float tile[64][65];
    const int bx = blockIdx.x * 64;   // col base
    const int by = blockIdx.y * 64;   // row base
    const int t  = threadIdx.x;
    const int c4 = (t & 15) * 4, r0 = t >> 4;
#pragma unroll
    for (int p = 0; p < 4; ++p) {
        const int r = r0 + p * 16;
        const float4 v = *(const float4*)&in[(size_t)(by + r) * NN + bx + c4];
        tile[r][c4 + 0] = v.x; tile[r][c4 + 1] = v.y;
        tile[r][c4 + 2] = v.z; tile[r][c4 + 3] = v.w;
        if (outN) {
            bf16x4 b = {(bf16)v.x, (bf16)v.y, (bf16)v.z, (bf16)v.w};
            *(bf16x4*)&outN[(size_t)(by + r) * NN + bx + c4] = b;
        }
    }
    __syncthreads();
    // outT[(bx+rw)][by+cc8 .. +7] = in[by+cc8+i][bx+rw] = tile[cc8+i][rw]
    const int cc8 = (t & 7) * 8, rw0 = t >> 3;
#pragma unroll
    for (int p = 0; p < 2; ++p) {
        const int rw = rw0 + p * 32;
        bf16x8 b;
#pragma unroll
        for (int i = 0; i < 8; ++i) b[i] = (bf16)tile[cc8 + i][rw];
        *(bf16x8*)&outT[(size_t)(bx + rw) * NN + by + cc8] = b;
    }
}

// ---------------------------------------------------------------------------
// Phase 1: z=0 -> DUAL GEMM sharing A:  M1 = A@W1, M2(out) = A@W2 for one
// 128x128 tile (12 ds_reads : 32 MFMA per wave-step), plus fused emission of
// M1bf = bf16(M1), B1bf = bf16(M1*W1).  z=1 -> M3 = W3@W3 plain.
// Depth-2 double buffer (48 KB LDS), XOR-swizzled columns, vmcnt pipeline.
// ---------------------------------------------------------------------------
struct P1Args {
    const bf16*  Abf;
    const bf16*  W1t;
    const bf16*  W2t;
    const bf16*  W3bf;
    const bf16*  W3t;
    float*       M1;
    float*       M2out;
    float*       M3;
    const float* W1;
    bf16*        M1bf;
    bf16*        B1bf;
};

__global__ __launch_bounds__(256, 2) void phase1_kernel(P1Args a) {
    __shared__ bf16 As0[128 * BK], As1[128 * BK];
    __shared__ bf16 B10[128 * BK], B11[128 * BK];
    __shared__ bf16 B20[128 * BK], B21[128 * BK];

    const int t  = threadIdx.x;
    const int bm = blockIdx.x * 128;
    const int bn = blockIdx.y * 128;

    const int row0 = t >> 2;
    const int qp   = t & 3;
    const int col0 = ((qp ^ ((row0 >> 1) & 3)) << 3);  // XOR swizzle
    const int off0 = t * 8;

    const int wave = t >> 6;
    const int lane = t & 63;
    const int wm   = (wave >> 1) * 64;
    const int wn   = (wave & 1) * 64;
    const int lrow = lane & 15;
    const int q    = lane >> 4;
    const int qe   = (q ^ ((lrow >> 1) & 3)) << 3;

    if (blockIdx.z == 0) {
        const bf16* gA  = a.Abf + (size_t)(bm + row0) * NN + col0;
        const bf16* gB1 = a.W1t + (size_t)(bn + row0) * NN + col0;
        const bf16* gB2 = a.W2t + (size_t)(bn + row0) * NN + col0;

        f32x4 acc1[4][4], acc2[4][4];
#pragma unroll
        for (int i = 0; i < 4; ++i)
#pragma unroll
            for (int j = 0; j < 4; ++j) {
                acc1[i][j] = (f32x4){0.f, 0.f, 0.f, 0.f};
                acc2[i][j] = (f32x4){0.f, 0.f, 0.f, 0.f};
            }

        auto issue = [&](bf16* As, bf16* B1, bf16* B2, int kt) {
            const int kof = kt * BK;
            async_copy16(&As[off0],           gA  + kof);
            async_copy16(&As[off0 + 64 * BK], gA  + (size_t)64 * NN + kof);
            async_copy16(&B1[off0],           gB1 + kof);
            async_copy16(&B1[off0 + 64 * BK], gB1 + (size_t)64 * NN + kof);
            async_copy16(&B2[off0],           gB2 + kof);
            async_copy16(&B2[off0 + 64 * BK], gB2 + (size_t)64 * NN + kof);
        };
        auto compute = [&](const bf16* As, const bf16* B1, const bf16* B2) {
            bf16x8 af[4], b1[4], b2[4];
#pragma unroll
            for (int i = 0; i < 4; ++i)
                af[i] = *(const bf16x8*)&As[(wm + i * 16 + lrow) * BK + qe];
#pragma unroll
            for (int j = 0; j < 4; ++j) {
                b1[j] = *(const bf16x8*)&B1[(wn + j * 16 + lrow) * BK + qe];
                b2[j] = *(const bf16x8*)&B2[(wn + j * 16 + lrow) * BK + qe];
            }
#pragma unroll
            for (int i = 0; i < 4; ++i)
#pragma unroll
                for (int j = 0; j < 4; ++j) {
                    acc1[i][j] = __builtin_amdgcn_mfma_f32_16x16x32_bf16(
                        af[i], b1[j], acc1[i][j], 0, 0, 0);
                    acc2[i][j] = __builtin_amdgcn_mfma_f32_16x16x32_bf16(
                        af[i], b2[j], acc2[i][j], 0, 0, 0);
                }
        };

        issue(As0, B10, B20, 0);
#pragma unroll 1
        for (int kt = 0; kt < 62; kt += 2) {
            issue(As1, B11, B21, kt + 1); WAIT_VM(6); BAR();
            compute(As0, B10, B20); BAR();
            issue(As0, B10, B20, kt + 2); WAIT_VM(6); BAR();
            compute(As1, B11, B21); BAR();
        }
        issue(As1, B11, B21, 63); WAIT_VM(6); BAR();
        compute(As0, B10, B20); BAR();
        WAIT_VM(0); BAR();
        compute(As1, B11, B21);

        // epilogue: M1, M2(out), M1bf, B1bf
#pragma unroll
        for (int i = 0; i < 4; ++i)
#pragma unroll
            for (int j = 0; j < 4; ++j)
#pragma unroll
                for (int r = 0; r < 4; ++r) {
                    const size_t idx =
                        (size_t)(bm + wm + i * 16 + q * 4 + r) * NN +
                        (bn + wn + j * 16 + lrow);
                    const float v1 = acc1[i][j][r];
                    a.M1[idx]    = v1;
                    a.M2out[idx] = acc2[i][j][r];
                    const float w = a.W1[idx];
                    a.M1bf[idx] = (bf16)v1;
                    a.B1bf[idx] = (bf16)(v1 * w);
                }
    } else {
        const bf16* gA = a.W3bf + (size_t)(bm + row0) * NN + col0;
        const bf16* gB = a.W3t  + (size_t)(bn + row0) * NN + col0;

        f32x4 acc[4][4];
#pragma unroll
        for (int i = 0; i < 4; ++i)
#pragma unroll
            for (int j = 0; j < 4; ++j) acc[i][j] = (f32x4){0.f, 0.f, 0.f, 0.f};

        auto issue = [&](bf16* As, bf16* Bs, int kt) {
            const int kof = kt * BK;
            async_copy16(&As[off0],           gA + kof);
            async_copy16(&As[off0 + 64 * BK], gA + (size_t)64 * NN + kof);
            async_copy16(&Bs[off0],           gB + kof);
            async_copy16(&Bs[off0 + 64 * BK], gB + (size_t)64 * NN + kof);
        };
        auto compute = [&](const bf16* As, const bf16* Bs) {
            bf16x8 af[4], bfr[4];
#pragma unroll
            for (int i = 0; i < 4; ++i)
                af[i] = *(const bf16x8*)&As[(wm + i * 16 + lrow) * BK + qe];
#pragma unroll
            for (int j = 0; j < 4; ++j)
                bfr[j] = *(const bf16x8*)&Bs[(wn + j * 16 + lrow) * BK + qe];
#pragma unroll
            for (int i = 0; i < 4; ++i)
#pragma unroll
                for (int j = 0; j < 4; ++j)
                    acc[i][j] = __builtin_amdgcn_mfma_f32_16x16x32_bf16(
                        af[i], bfr[j], acc[i][j], 0, 0, 0);
        };

        issue(As0, B10, 0);
#pragma unroll 1
        for (int kt = 0; kt < 62; kt += 2) {
            issue(As1, B11, kt + 1); WAIT_VM(4); BAR();
            compute(As0, B10); BAR();
            issue(As0, B10, kt + 2); WAIT_VM(4); BAR();
            compute(As1, B11); BAR();
        }
        issue(As1, B11, 63); WAIT_VM(4); BAR();
        compute(As0, B10); BAR();
        WAIT_VM(0); BAR();
        compute(As1, B11);

#pragma unroll
        for (int i = 0; i < 4; ++i)
#pragma unroll
            for (int j = 0; j < 4; ++j)
#pragma unroll
                for (int r = 0; r < 4; ++r)
                    a.M3[(size_t)(bm + wm + i * 16 + q * 4 + r) * NN +
                         (bn + wn + j * 16 + lrow)] = acc[i][j][r];
    }
}

// ---------------------------------------------------------------------------
// Phase 2: fused dual GEMM + final epilogue, 128x64 tile, BK=32, depth-3.
// Waves tiled 4x1 (wave tile 32x64 per matrix): 8 ds_reads : 16 MFMA.
//   m5 = M1bf @ A,  m4 = B1bf @ A   (A given as At = A^T), shared B frags;
//   out = M1*M2 + M1 + M3 + M3*(m4*W1)*(M3 + m5)    (M2 resides in out)
// ---------------------------------------------------------------------------
struct Gemm2Args {
    const bf16*  M1bf;
    const bf16*  B1bf;
    const bf16*  At;
    const float* M1;
    const float* M3;
    const float* W1;
    float*       out;
};

__global__ __launch_bounds__(256, 2) void gemm2_fused_kernel(Gemm2Args args) {
    __shared__ bf16 A50[128 * BK], A51[128 * BK], A52[128 * BK];  // M1bf
    __shared__ bf16 A40[128 * BK], A41[128 * BK], A42[128 * BK];  // B1bf
    __shared__ bf16 Bs0[64 * BK],  Bs1[64 * BK],  Bs2[64 * BK];   // At

    const int t  = threadIdx.x;
    const int bm = blockIdx.x * 128;
    const int bn = blockIdx.y * 64;

    const int row0 = t >> 2;
    const int qp   = t & 3;
    const int col0 = ((qp ^ ((row0 >> 1) & 3)) << 3);
    const int off0 = t * 8;

    const bf16* g5 = args.M1bf + (size_t)(bm + row0) * NN + col0;
    const bf16* g4 = args.B1bf + (size_t)(bm + row0) * NN + col0;
    const bf16* gB = args.At   + (size_t)(bn + row0) * NN + col0;

    const int wave = t >> 6;
    const int lane = t & 63;
    const int wm   = wave * 32;          // 4x1 wave tiling
    const int lrow = lane & 15;
    const int q    = lane >> 4;
    const int qe   = (q ^ ((lrow >> 1) & 3)) << 3;

    f32x4 acc5[2][4], acc4[2][4];
#pragma unroll
    for (int i = 0; i < 2; ++i)
#pragma unroll
        for (int j = 0; j < 4; ++j) {
            acc5[i][j] = (f32x4){0.f, 0.f, 0.f, 0.f};
            acc4[i][j] = (f32x4){0.f, 0.f, 0.f, 0.f};
        }

    auto issue = [&](bf16* A5, bf16* A4, bf16* Bs, int kt) {
        const int kof = kt * BK;
        async_copy16(&A5[off0],           g5 + kof);
        async_copy16(&A5[off0 + 64 * BK], g5 + (size_t)64 * NN + kof);
        async_copy16(&A4[off0],           g4 + kof);
        async_copy16(&A4[off0 + 64 * BK], g4 + (size_t)64 * NN + kof);
        async_copy16(&Bs[off0],           gB + kof);
    };
    auto compute = [&](const bf16* A5, const bf16* A4, const bf16* Bs) {
        bf16x8 a5[2], a4[2], bfr[4];
#pragma unroll
        for (int i = 0; i < 2; ++i) {
            a5[i] = *(const bf16x8*)&A5[(wm + i * 16 + lrow) * BK + qe];
            a4[i] = *(const bf16x8*)&A4[(wm + i * 16 + lrow) * BK + qe];
        }
#pragma unroll
        for (int j = 0; j < 4; ++j)
            bfr[j] = *(const bf16x8*)&Bs[(j * 16 + lrow) * BK + qe];
#pragma unroll
        for (int i = 0; i < 2; ++i)
#pragma unroll
            for (int j = 0; j < 4; ++j) {
                acc5[i][j] = __builtin_amdgcn_mfma_f32_16x16x32_bf16(
                    a5[i], bfr[j], acc5[i][j], 0, 0, 0);
                acc4[i][j] = __builtin_amdgcn_mfma_f32_16x16x32_bf16(
                    a4[i], bfr[j], acc4[i][j], 0, 0, 0);
            }
    };

    issue(A50, A40, Bs0, 0);
    issue(A51, A41, Bs1, 1);
#pragma unroll 1
    for (int kt = 0; kt < 60; kt += 3) {
        issue(A52, A42, Bs2, kt + 2); WAIT_VM(10); BAR(); compute(A50, A40, Bs0); BAR();
        issue(A50, A40, Bs0, kt + 3); WAIT_VM(10); BAR(); compute(A51, A41, Bs1); BAR();
        issue(A51, A41, Bs1, kt + 4); WAIT_VM(10); BAR(); compute(A52, A42, Bs2); BAR();
    }
    issue(A52, A42, Bs2, 62); WAIT_VM(10); BAR(); compute(A50, A40, Bs0); BAR();
    issue(A50, A40, Bs0, 63); WAIT_VM(10); BAR(); compute(A51, A41, Bs1); BAR();
    WAIT_VM(5); BAR(); compute(A52, A42, Bs2); BAR();
    WAIT_VM(0); BAR(); compute(A50, A40, Bs0);

    // fused final epilogue: out = M1*M2 + M1 + M3 + M3*(m4*W1)*(M3 + m5)
#pragma unroll
    for (int i = 0; i < 2; ++i)
#pragma unroll
        for (int j = 0; j < 4; ++j)
#pragma unroll
            for (int r = 0; r < 4; ++r) {
                const size_t idx = (size_t)(bm + wm + i * 16 + q * 4 + r) * NN +
                                   (bn + j * 16 + lrow);
                const float m5 = acc5[i][j][r];
                const float m4 = acc4[i][j][r];
                const float m1 = args.M1[idx];
                const float m3 = args.M3[idx];
                const float w1 = args.W1[idx];
                const float m2 = args.out[idx];
                args.out[idx] =
                    m1 * m2 + m1 + m3 + m3 * (m4 * w1) * (m3 + m5);
            }
}

// ---------------------------------------------------------------------------
extern "C" void kernel_launch(void* const* d_in, const int* in_sizes, int n_in,
                              void* d_out, int out_size, void* d_ws, size_t ws_size,
                              hipStream_t stream) {
    const float* A  = (const float*)d_in[0];
    const float* W1 = (const float*)d_in[1];
    const float* W2 = (const float*)d_in[2];
    const float* W3 = (const float*)d_in[3];
    float* out = (float*)d_out;

    const size_t P = (size_t)NN * NN;
    char* ws = (char*)d_ws;

    bf16* Abf  = (bf16*)ws;            // P*2 bytes each
    bf16* At   = Abf + P;
    bf16* W1t  = At + P;
    bf16* W2t  = W1t + P;
    bf16* W3bf = W2t + P;
    bf16* W3t  = W3bf + P;
    bf16* M1bf = W3t + P;
    bf16* B1bf = M1bf + P;
    float* M1  = (float*)(B1bf + P);   // P*4 bytes each
    float* M3  = M1 + P;
    // total: 8*2*P + 2*4*P = 24*P = 96 MiB

    CastArgs ca;
    ca.in[0] = A;  ca.outT[0] = At;  ca.outN[0] = Abf;
    ca.in[1] = W1; ca.outT[1] = W1t; ca.outN[1] = nullptr;
    ca.in[2] = W2; ca.outT[2] = W2t; ca.outN[2] = nullptr;
    ca.in[3] = W3; ca.outT[3] = W3t; ca.outN[3] = W3bf;
    transpose_cast_kernel<<<dim3(NN / 64, NN / 64, 4), 256, 0, stream>>>(ca);

    // phase 1: z=0 dual (M1 = A@W1, M2 = A@W2, + M1bf/B1bf), z=1 M3 = W3@W3
    P1Args p1;
    p1.Abf = Abf; p1.W1t = W1t; p1.W2t = W2t; p1.W3bf = W3bf; p1.W3t = W3t;
    p1.M1 = M1; p1.M2out = out; p1.M3 = M3;
    p1.W1 = W1; p1.M1bf = M1bf; p1.B1bf = B1bf;
    phase1_kernel<<<dim3(NN / 128, NN / 128, 2), 256, 0, stream>>>(p1);

    // phase 2: fused dual GEMM (m5 = M1@A, m4 = (M1*W1)@A) + final epilogue
    Gemm2Args g2;
    g2.M1bf = M1bf; g2.B1bf = B1bf; g2.At = At;
    g2.M1 = M1; g2.M3 = M3; g2.W1 = W1; g2.out = out;
    gemm2_fused_kernel<<<dim3(NN / 128, NN / 64), 256, 0, stream>>>(g2);
}